// Round 10
// baseline (297.742 us; speedup 1.0000x reference)
//
#include <hip/hip_runtime.h>

#define D 128
#define N_SRC 100000
#define N_DST 100000
#define N_EDGES 640000

#define SCAN_BLK 1024
#define N_SCAN_BLOCKS ((N_DST + SCAN_BLK - 1) / SCAN_BLK)   // 98

#define SCAT_BLOCKS ((N_EDGES + 255) / 256)                 // 2500
#define CVT_BLOCKS  ((N_SRC * D / 8) / 256)                 // 6250 (exact)
#define PACKW_BLOCKS 128

typedef __attribute__((ext_vector_type(8))) short s8v;
typedef __attribute__((ext_vector_type(4))) float f32x4;

__device__ __forceinline__ unsigned short f2bf(float f) {
    unsigned int u = __float_as_uint(f);
    u += 0x7fffu + ((u >> 16) & 1u);   // round-to-nearest-even
    return (unsigned short)(u >> 16);
}

__device__ __forceinline__ unsigned int pk2(float a, float b) {
    return (unsigned int)f2bf(a) | ((unsigned int)f2bf(b) << 16);
}

// ---- hist: critical-path head, nothing else bundled ---------------------
__global__ __launch_bounds__(256) void hist_kernel(
    const int* __restrict__ dst_idx, int* __restrict__ counts)
{
    int e = blockIdx.x * 256 + threadIdx.x;
    if (e < N_EDGES) atomicAdd(&counts[dst_idx[e]], 1);
}

__global__ __launch_bounds__(256) void scan_blocks(
    const int* __restrict__ counts, int* __restrict__ row_start,
    int* __restrict__ block_sums)
{
    __shared__ int sh[256];
    const int tid = threadIdx.x;
    const int base = blockIdx.x * SCAN_BLK + tid * 4;
    int v[4];
    int local = 0;
#pragma unroll
    for (int k = 0; k < 4; k++) {
        int idx = base + k;
        v[k] = (idx < N_DST) ? counts[idx] : 0;
        local += v[k];
    }
    sh[tid] = local;
    __syncthreads();
    for (int off = 1; off < 256; off <<= 1) {
        int t = (tid >= off) ? sh[tid - off] : 0;
        __syncthreads();
        sh[tid] += t;
        __syncthreads();
    }
    int run = (tid == 0) ? 0 : sh[tid - 1];
    if (tid == 255) block_sums[blockIdx.x] = sh[255];
#pragma unroll
    for (int k = 0; k < 4; k++) {
        int idx = base + k;
        if (idx < N_DST) row_start[idx] = run;
        run += v[k];
    }
}

// top-scan of the 98 block sums done redundantly per block in LDS.
__global__ __launch_bounds__(256) void add_offsets(
    int* __restrict__ row_start, const int* __restrict__ block_sums,
    int* __restrict__ cursor)
{
    __shared__ int sh[128];
    const int tid = threadIdx.x;
    if (tid < 128) sh[tid] = (tid < N_SCAN_BLOCKS) ? block_sums[tid] : 0;
    __syncthreads();
    for (int off = 1; off < 128; off <<= 1) {
        int t = (tid < 128 && tid >= off) ? sh[tid - off] : 0;
        __syncthreads();
        if (tid < 128) sh[tid] += t;
        __syncthreads();
    }
    int i = blockIdx.x * 256 + tid;
    if (i < N_DST) {
        int blk = i / SCAN_BLK;
        int off = (blk == 0) ? 0 : sh[blk - 1];
        int v = row_start[i] + off;
        row_start[i] = v;
        cursor[i] = v;
    }
    if (i == 0) row_start[N_DST] = N_EDGES;
}

// ---- scatter + cvt + packW in ONE launch --------------------------------
__global__ __launch_bounds__(256) void scatter_cvt(
    const int* __restrict__ src_idx, const int* __restrict__ dst_idx,
    int* __restrict__ cursor, int* __restrict__ edge_src,
    const float* __restrict__ h_src, unsigned int* __restrict__ mir32,
    const float* __restrict__ W, unsigned short* __restrict__ Bp)
{
    const int blk = blockIdx.x;
    const int tid = threadIdx.x;
    if (blk < SCAT_BLOCKS) {
        int e = blk * 256 + tid;
        if (e < N_EDGES) {
            int d = dst_idx[e];
            int pos = atomicAdd(&cursor[d], 1);
            edge_src[pos] = src_idx[e];
        }
    } else if (blk < SCAT_BLOCKS + CVT_BLOCKS) {
        int id = (blk - SCAT_BLOCKS) * 256 + tid;      // [0, 1.6e6)
        const float4* p = (const float4*)(h_src + (size_t)id * 8);
        float4 x = p[0], y = p[1];
        uint4 o;
        o.x = pk2(x.x, x.y); o.y = pk2(x.z, x.w);
        o.z = pk2(y.x, y.y); o.w = pk2(y.z, y.w);
        *(uint4*)(mir32 + (size_t)(id >> 4) * 64 + (id & 15) * 4) = o;
    } else {
        int id = (blk - SCAT_BLOCKS - CVT_BLOCKS) * 256 + tid;
        if (id < 32768) {
            int j = id & 7;
            int l = (id >> 3) & 63;
            int t = (id >> 9) & 7;
            int s = id >> 12;
            int k = s * 32 + (l >> 4) * 8 + j;
            int n = t * 16 + (l & 15);
            Bp[id] = f2bf(W[k * D + n]);
        }
    }
}

// ============ FUSED gather(+DMA staging) + projection ====================
// 1 wave / block, 16 rows. The gather stages edge rows via
// global_load_lds width=16 (async DMA, zero VGPR cost): per instruction,
// 4 edge rows of 256 B land linearly in gbuf (lin dest + lin read = rule
// 21 ok). Up to 32 edges (8 KB) outstanding per wave under one vmcnt —
// MLP no longer subject to the register allocator (R9's VGPR=32 showed
// the compiler serializing the VGPR-staged batch). hN stays XOR-swizzled
// for the conflict-free frag reads.
__global__ __launch_bounds__(64) void fused_ag(
    const float* __restrict__ h_dst,
    const unsigned short* __restrict__ mir,   // dense [N_SRC][128] bf16
    const int* __restrict__ row_start,
    const int* __restrict__ edge_src,
    const unsigned short* __restrict__ Bp,
    const float* __restrict__ bias,
    float* __restrict__ out)
{
    __shared__ unsigned int gbuf[32 * 64];   // 8 KB: 32 edge slots x 256 B
    __shared__ char hN[4096];                // 16 rows x 256 B (swizzled)

    const int lane = threadIdx.x;            // 0..63
    const int quad = lane >> 4;
    const int lr = lane & 15;
    const int rw0 = blockIdx.x * 16;         // N_DST = 6250*16 exactly

    // ---- h_dst loads + convert to bf16 A fragments (before the gather)
    const float* p0 = h_dst + (size_t)(rw0 + lr) * D + quad * 8;
    s8v af0[4];
#pragma unroll
    for (int s = 0; s < 4; s++) {
        float4 x = *(const float4*)(p0 + s * 32);
        float4 y = *(const float4*)(p0 + s * 32 + 4);
        unsigned short u0[8];
        u0[0]=f2bf(x.x); u0[1]=f2bf(x.y); u0[2]=f2bf(x.z); u0[3]=f2bf(x.w);
        u0[4]=f2bf(y.x); u0[5]=f2bf(y.y); u0[6]=f2bf(y.z); u0[7]=f2bf(y.w);
        af0[s] = *(s8v*)u0;
    }

    // ---- gather: one row at a time, whole wave; DMA-staged batches
    for (int r = 0; r < 16; ++r) {
        const int row = rw0 + r;
        const int start = __builtin_amdgcn_readfirstlane(row_start[row]);
        const int deg = __builtin_amdgcn_readfirstlane(row_start[row + 1]) - start;
        float a0 = 0.f, a1 = 0.f;
        for (int cb = 0; cb < deg; cb += 32) {
            const int cnt = min(deg - cb, 32);
            // edge ids for this chunk: lane e holds id of edge cb+e (clamped)
            int vid = edge_src[start + min(cb + lane, deg - 1)];
            // issue ceil(cnt/4) DMA instructions; each moves 4 edge rows
            for (int e = 0; e < cnt; e += 4) {
                int s = __shfl(vid, e + quad);        // edge (e+quad)'s src row
                const char* gp = (const char*)mir + ((size_t)s * 256 + lr * 16);
                __builtin_amdgcn_global_load_lds(
                    (const __attribute__((address_space(1))) void*)gp,
                    (__attribute__((address_space(3))) void*)&gbuf[e * 64],
                    16, 0, 0);
            }
            asm volatile("s_waitcnt vmcnt(0)" ::: "memory");
            __builtin_amdgcn_sched_barrier(0);
            // accumulate: lane owns cols 2*lane, 2*lane+1 of the row
            for (int e = 0; e < cnt; ++e) {
                unsigned int u = gbuf[e * 64 + lane];
                a0 += __uint_as_float(u << 16);
                a1 += __uint_as_float(u & 0xffff0000u);
            }
        }
        const float inv = 1.0f / fmaxf((float)deg, 1.0f);
        unsigned int pw = pk2(a0 * inv, a1 * inv);
        int ba = (r * 256 + lane * 4) ^ ((r & 7) << 4);   // swizzled store
        *(unsigned int*)(hN + ba) = pw;
    }

    // ---- read back h_N fragments (in-wave LDS dep; compiler waits)
    s8v an[4];
#pragma unroll
    for (int s = 0; s < 4; s++) {
        int ba = (lr * 256 + s * 64 + quad * 16) ^ ((lr & 7) << 4);
        an[s] = *(const s8v*)(hN + ba);
    }

    f32x4 acc[8];
#pragma unroll
    for (int t = 0; t < 8; t++) acc[t] = (f32x4){0.f, 0.f, 0.f, 0.f};

    // ---- MFMA: K=0..127 from h_dst frags, K=128..255 from h_N frags
#pragma unroll
    for (int s = 0; s < 8; s++) {
        s8v a0 = (s < 4) ? af0[s] : an[s - 4];
#pragma unroll
        for (int t = 0; t < 8; t++) {
            s8v bf = *(const s8v*)(Bp + ((size_t)(s * 8 + t) * 64 + lane) * 8);
            acc[t] = __builtin_amdgcn_mfma_f32_16x16x32_bf16(a0, bf, acc[t], 0, 0, 0);
        }
    }

    // ---- epilogue
#pragma unroll
    for (int t = 0; t < 8; t++) {
        float bv = bias[t * 16 + lr];
#pragma unroll
        for (int r = 0; r < 4; r++) {
            int row = rw0 + quad * 4 + r;
            out[(size_t)row * D + t * 16 + lr] = acc[t][r] + bv;
        }
    }
}

extern "C" void kernel_launch(void* const* d_in, const int* in_sizes, int n_in,
                              void* d_out, int out_size, void* d_ws, size_t ws_size,
                              hipStream_t stream) {
    const float* h_src  = (const float*)d_in[0];
    const float* h_dst  = (const float*)d_in[1];
    const int* src_idx  = (const int*)d_in[2];
    const int* dst_idx  = (const int*)d_in[3];
    const float* W      = (const float*)d_in[4];
    const float* b      = (const float*)d_in[5];
    float* out = (float*)d_out;

    // Workspace: Bp | CSR ints | edge_src | dense bf16 mirror (~29.5 MB)
    unsigned short* Bp = (unsigned short*)d_ws;         // 32768 u16 = 64 KB
    int* ws_i          = (int*)((char*)d_ws + 65536);
    int* row_start     = ws_i;                          // N_DST+1
    int* cursor        = row_start + (N_DST + 1);       // N_DST
    int* counts        = cursor + N_DST;                // N_DST
    int* block_sums    = counts + N_DST;                // N_SCAN_BLOCKS
    int* edge_src      = block_sums + N_SCAN_BLOCKS;    // N_EDGES

    size_t int_bytes = (size_t)(N_DST + 1 + N_DST + N_DST + N_SCAN_BLOCKS
                                + N_EDGES) * 4;
    size_t mir_off   = (65536 + int_bytes + 255) & ~(size_t)255;
    unsigned short* mir = (unsigned short*)((char*)d_ws + mir_off);

    hipMemsetAsync(counts, 0, (size_t)N_DST * sizeof(int), stream);

    // critical path: hist -> scan -> add -> scatter
    hist_kernel<<<(N_EDGES + 255) / 256, 256, 0, stream>>>(dst_idx, counts);
    scan_blocks<<<N_SCAN_BLOCKS, 256, 0, stream>>>(counts, row_start, block_sums);
    add_offsets<<<(N_DST + 255) / 256, 256, 0, stream>>>(row_start, block_sums, cursor);

    // scatter (latency-bound) overlapped with cvt+packW (BW-bound)
    scatter_cvt<<<SCAT_BLOCKS + CVT_BLOCKS + PACKW_BLOCKS, 256, 0, stream>>>(
        src_idx, dst_idx, cursor, edge_src,
        h_src, (unsigned int*)mir, W, Bp);

    fused_ag<<<N_DST / 16, 64, 0, stream>>>(
        h_dst, mir, row_start, edge_src, Bp, b, out);
}